// Round 1
// baseline (701.282 us; speedup 1.0000x reference)
//
#include <hip/hip_runtime.h>

// EGNN fused layer, M=1024 nodes, n=hid=64, fp32.
// Kernel 1: pe_i(+be1), pe_j precompute (h @ We1 row-splits).
// Kernel 2: per-node-i block; per-edge fused phi_e -> m -> phi_x -> s,
//           register accumulation of m_i and x-update, fused phi_h epilogue.

#define MM 1024
#define WST 68   // LDS row stride for 64-wide weight rows (16B-aligned, bank-spread)

__device__ __forceinline__ float fsilu(float v) {
    // x * sigmoid(x) = x / (1 + exp(-x)); rcp approx (~1 ulp) is fine vs fp32 ref
    float e = __expf(-v);
    return v * __builtin_amdgcn_rcpf(1.0f + e);
}

__global__ void __launch_bounds__(64) egnn_pre(
    const float* __restrict__ h, const float* __restrict__ We1,
    const float* __restrict__ be1,
    float* __restrict__ peib, float* __restrict__ pej)
{
    const int i = blockIdx.x;
    const int c = threadIdx.x;
    __shared__ float hrow[64];
    hrow[c] = h[i * 64 + c];
    __syncthreads();
    float acc1 = be1[c];
    float acc2 = 0.0f;
#pragma unroll 8
    for (int cp = 0; cp < 64; ++cp) {
        const float hv = hrow[cp];
        acc1 = fmaf(hv, We1[cp * 64 + c], acc1);           // We1[:64]
        acc2 = fmaf(hv, We1[(64 + cp) * 64 + c], acc2);    // We1[64:128]
    }
    peib[i * 64 + c] = acc1;
    pej[i * 64 + c]  = acc2;
}

__global__ void __launch_bounds__(256, 2) egnn_main(
    const float* __restrict__ x, const float* __restrict__ a,
    const float* __restrict__ h, const float* __restrict__ We1,
    const float* __restrict__ peib, const float* __restrict__ pej,
    const float* __restrict__ We2, const float* __restrict__ be2,
    const float* __restrict__ Wx1, const float* __restrict__ bx1,
    const float* __restrict__ Wx2, const float* __restrict__ bx2,
    const float* __restrict__ Wh1, const float* __restrict__ bh1,
    const float* __restrict__ Wh2, const float* __restrict__ bh2,
    float* __restrict__ out)
{
    const int i = blockIdx.x;
    const int tid = threadIdx.x;
    const int lane = tid & 63;
    const int wid = tid >> 6;

    __shared__ float we2_lds[64 * WST];    // row-major rows of We2
    __shared__ float wx1t_lds[64 * WST];   // Wx1 transposed: row kk holds Wx1[:,kk]
    __shared__ float4 quad_lds[64];        // (peib_i[c], w_d2[c], w_a[c], be2[c])
    __shared__ float2 quad2_lds[64];       // (bx1[kk], Wx2[kk])
    __shared__ float partial[4 * 64];
    __shared__ float xpart[4][3];
    __shared__ float mi_lds[64];
    __shared__ float hrow_lds[64];
    __shared__ float hid1_lds[64];

    // --- stage weights ---
    for (int idx = tid; idx < 4096; idx += 256) {
        const int r = idx >> 6, q = idx & 63;
        we2_lds[r * WST + q] = We2[idx];        // coalesced write
        wx1t_lds[q * WST + r] = Wx1[idx];       // transpose (one-time conflicts ok)
    }
    if (tid < 64) {
        quad_lds[tid]  = make_float4(peib[i * 64 + tid],
                                     We1[128 * 64 + tid],
                                     We1[129 * 64 + tid],
                                     be2[tid]);
        quad2_lds[tid] = make_float2(bx1[tid], Wx2[tid]);
    }
    __syncthreads();

    const float xi0 = x[i * 3 + 0], xi1 = x[i * 3 + 1], xi2 = x[i * 3 + 2];
    const float bx2v = bx2[0];

    float micc[64];
#pragma unroll
    for (int k = 0; k < 64; ++k) micc[k] = 0.0f;
    float xa0 = 0.0f, xa1 = 0.0f, xa2 = 0.0f;

    for (int jt = 0; jt < MM; jt += 256) {
        const int j = jt + tid;
        const float xj0 = x[j * 3 + 0], xj1 = x[j * 3 + 1], xj2 = x[j * 3 + 2];
        const float d0 = xi0 - xj0, d1 = xi1 - xj1, d2v = xi2 - xj2;
        const float dd = d0 * d0 + d1 * d1 + d2v * d2v;
        const float av = a[i * MM + j];
        const float* __restrict__ pejrow = pej + j * 64;

        float macc[64];
#pragma unroll
        for (int k = 0; k < 64; ++k) macc[k] = 0.0f;

        // ---- GEMV-1 fused: macc[k] += silu(pre_c) * We2[c][k] ----
        for (int c4 = 0; c4 < 16; ++c4) {
            const float4 pj = *reinterpret_cast<const float4*>(pejrow + c4 * 4);
#pragma unroll
            for (int u = 0; u < 4; ++u) {
                const int c = c4 * 4 + u;
                const float4 q = quad_lds[c];
                float pre = q.x + ((u == 0) ? pj.x : (u == 1) ? pj.y : (u == 2) ? pj.z : pj.w);
                pre = fmaf(dd, q.y, pre);
                pre = fmaf(av, q.z, pre);
                const float ps = fsilu(pre);
                const float* wr = &we2_lds[c * WST];
#pragma unroll
                for (int k4 = 0; k4 < 16; ++k4) {
                    const float4 w = *reinterpret_cast<const float4*>(wr + k4 * 4);
                    macc[k4 * 4 + 0] = fmaf(ps, w.x, macc[k4 * 4 + 0]);
                    macc[k4 * 4 + 1] = fmaf(ps, w.y, macc[k4 * 4 + 1]);
                    macc[k4 * 4 + 2] = fmaf(ps, w.z, macc[k4 * 4 + 2]);
                    macc[k4 * 4 + 3] = fmaf(ps, w.w, macc[k4 * 4 + 3]);
                }
            }
        }

        // ---- m = silu(macc + be2); accumulate m_i (skip self-edge) ----
        const bool notself = (j != i);
#pragma unroll
        for (int k = 0; k < 64; ++k) {
            const float m = fsilu(macc[k] + quad_lds[k].w);
            macc[k] = m;
            if (notself) micc[k] += m;
        }

        // ---- phi_x fused: s = bx2 + sum_kk silu(bx1+m@Wx1[:,kk]) * Wx2[kk] ----
        float s = bx2v;
        for (int kk = 0; kk < 64; ++kk) {
            const float2 q2 = quad2_lds[kk];
            const float* wr = &wx1t_lds[kk * WST];
            float t0 = q2.x, t1 = 0.0f, t2 = 0.0f, t3 = 0.0f;
#pragma unroll
            for (int k4 = 0; k4 < 16; ++k4) {
                const float4 w = *reinterpret_cast<const float4*>(wr + k4 * 4);
                t0 = fmaf(macc[k4 * 4 + 0], w.x, t0);
                t1 = fmaf(macc[k4 * 4 + 1], w.y, t1);
                t2 = fmaf(macc[k4 * 4 + 2], w.z, t2);
                t3 = fmaf(macc[k4 * 4 + 3], w.w, t3);
            }
            const float t = (t0 + t1) + (t2 + t3);
            s = fmaf(fsilu(t), q2.y, s);
        }

        xa0 = fmaf(d0, s, xa0);
        xa1 = fmaf(d1, s, xa1);
        xa2 = fmaf(d2v, s, xa2);
    }

    // ---- block-level reductions ----
#pragma unroll
    for (int k = 0; k < 64; ++k) {
        float v = micc[k];
        v += __shfl_xor(v, 1);
        v += __shfl_xor(v, 2);
        v += __shfl_xor(v, 4);
        v += __shfl_xor(v, 8);
        v += __shfl_xor(v, 16);
        v += __shfl_xor(v, 32);
        if (lane == 0) partial[wid * 64 + k] = v;
    }
    {
        float v0 = xa0, v1 = xa1, v2 = xa2;
        for (int sft = 1; sft < 64; sft <<= 1) {
            v0 += __shfl_xor(v0, sft);
            v1 += __shfl_xor(v1, sft);
            v2 += __shfl_xor(v2, sft);
        }
        if (lane == 0) { xpart[wid][0] = v0; xpart[wid][1] = v1; xpart[wid][2] = v2; }
    }
    __syncthreads();

    if (tid < 64) {
        mi_lds[tid] = partial[tid] + partial[64 + tid] + partial[128 + tid] + partial[192 + tid];
        hrow_lds[tid] = h[i * 64 + tid];
    }
    __syncthreads();

    // phi_h layer 1: hid1[kk] = silu(bh1 + h_i@Wh1[:64,kk] + m_i@Wh1[64:,kk])
    if (tid < 64) {
        const int kk = tid;
        float acc0 = bh1[kk], acc1 = 0.0f;
#pragma unroll 8
        for (int c = 0; c < 64; ++c) {
            acc0 = fmaf(hrow_lds[c], Wh1[c * 64 + kk], acc0);
            acc1 = fmaf(mi_lds[c], Wh1[(64 + c) * 64 + kk], acc1);
        }
        hid1_lds[kk] = fsilu(acc0 + acc1);
    }
    __syncthreads();

    // phi_h layer 2 -> h_new
    if (tid < 64) {
        const int c = tid;
        float acc = bh2[c];
#pragma unroll 8
        for (int kk = 0; kk < 64; ++kk) acc = fmaf(hid1_lds[kk], Wh2[kk * 64 + c], acc);
        out[3072 + i * 64 + c] = acc;
    }
    // x_new
    if (tid == 0) {
        const float C = 1.0f / 1023.0f;
        const float s0 = xpart[0][0] + xpart[1][0] + xpart[2][0] + xpart[3][0];
        const float s1 = xpart[0][1] + xpart[1][1] + xpart[2][1] + xpart[3][1];
        const float s2 = xpart[0][2] + xpart[1][2] + xpart[2][2] + xpart[3][2];
        out[i * 3 + 0] = xi0 + C * s0;
        out[i * 3 + 1] = xi1 + C * s1;
        out[i * 3 + 2] = xi2 + C * s2;
    }
}

extern "C" void kernel_launch(void* const* d_in, const int* in_sizes, int n_in,
                              void* d_out, int out_size, void* d_ws, size_t ws_size,
                              hipStream_t stream) {
    const float* x   = (const float*)d_in[0];
    const float* a   = (const float*)d_in[1];
    const float* h   = (const float*)d_in[2];
    const float* We1 = (const float*)d_in[3];
    const float* be1 = (const float*)d_in[4];
    const float* We2 = (const float*)d_in[5];
    const float* be2 = (const float*)d_in[6];
    const float* Wx1 = (const float*)d_in[7];
    const float* bx1 = (const float*)d_in[8];
    const float* Wx2 = (const float*)d_in[9];
    const float* bx2 = (const float*)d_in[10];
    const float* Wh1 = (const float*)d_in[11];
    const float* bh1 = (const float*)d_in[12];
    const float* Wh2 = (const float*)d_in[13];
    const float* bh2 = (const float*)d_in[14];
    float* out = (float*)d_out;

    float* peib = (float*)d_ws;                 // [1024,64]
    float* pej  = peib + 1024 * 64;             // [1024,64]

    egnn_pre<<<dim3(1024), dim3(64), 0, stream>>>(h, We1, be1, peib, pej);
    egnn_main<<<dim3(1024), dim3(256), 0, stream>>>(
        x, a, h, We1, peib, pej, We2, be2, Wx1, bx1, Wx2, bx2,
        Wh1, bh1, Wh2, bh2, out);
}

// Round 3
// 177.666 us; speedup vs baseline: 3.9472x; 3.9472x over previous
//
#include <hip/hip_runtime.h>

// EGNN fused layer via MFMA, M=1024, n=hid=64.
// GEMMs computed transposed: D1 = We2^T @ P^T, T^T = Wx1^T @ m^T so each lane
// keeps its own j (= lane&15) end-to-end. We2 split fp16 hi/lo, Wx1 single fp16.

#define MM 1024

typedef _Float16 half8 __attribute__((ext_vector_type(8)));
typedef float f32x4 __attribute__((ext_vector_type(4)));
typedef int int4t __attribute__((ext_vector_type(4)));

__device__ __forceinline__ float fsilu(float v) {
    float e = __expf(-v);
    return v * __builtin_amdgcn_rcpf(1.0f + e);
}

// blocks 0..255: pe_i(+be1)/pe_j precompute (4 nodes per block)
// blocks 256..287: pack We2 (fp16 hi/lo) and Wx1 (fp16) into MFMA A-fragment order
__global__ void __launch_bounds__(256) egnn_prepack(
    const float* __restrict__ h, const float* __restrict__ We1,
    const float* __restrict__ be1, const float* __restrict__ We2,
    const float* __restrict__ Wx1,
    float* __restrict__ peib, float* __restrict__ pej,
    _Float16* __restrict__ we2hi, _Float16* __restrict__ we2lo,
    _Float16* __restrict__ wx1h)
{
    const int b = blockIdx.x;
    if (b < 256) {
        const int i = b * 4 + (threadIdx.x >> 6);
        const int c = threadIdx.x & 63;
        float acc1 = be1[c], acc2 = 0.0f;
        const float* __restrict__ hrow = h + i * 64;
#pragma unroll 8
        for (int cp = 0; cp < 64; ++cp) {
            const float hv = hrow[cp];
            acc1 = fmaf(hv, We1[cp * 64 + c], acc1);
            acc2 = fmaf(hv, We1[(64 + cp) * 64 + c], acc2);
        }
        peib[i * 64 + c] = acc1;
        pej[i * 64 + c]  = acc2;
    } else {
        const int idx = (b - 256) * 256 + threadIdx.x;   // 0..8191
        const int e = idx & 7, l = (idx >> 3) & 63, f = (idx >> 9) & 7;
        const int n = f >> 1, s = f & 1;
        const int outc = 16 * n + (l & 15);              // output row (k or kk)
        const int kc   = 32 * s + ((l >> 4) * 8) + e;    // contraction index
        if (idx < 4096) {
            const float wv = We2[kc * 64 + outc];        // We2^T[k][c]
            const _Float16 hi = (_Float16)wv;
            we2hi[idx] = hi;
            we2lo[idx] = (_Float16)(wv - (float)hi);
        } else {
            const float wv = Wx1[kc * 64 + outc];        // Wx1^T[kk][k]
            wx1h[idx - 4096] = (_Float16)wv;
        }
    }
}

__global__ void __launch_bounds__(256, 2) egnn_main(
    const float* __restrict__ x, const float* __restrict__ a,
    const float* __restrict__ h, const float* __restrict__ We1,
    const float* __restrict__ peib, const float* __restrict__ pej,
    const _Float16* __restrict__ we2hi, const _Float16* __restrict__ we2lo,
    const _Float16* __restrict__ wx1h,
    const float* __restrict__ be2,
    const float* __restrict__ bx1, const float* __restrict__ Wx2,
    const float* __restrict__ bx2,
    const float* __restrict__ Wh1, const float* __restrict__ bh1,
    const float* __restrict__ Wh2, const float* __restrict__ bh2,
    float* __restrict__ out)
{
    const int i = blockIdx.x;
    const int tid = threadIdx.x;
    const int w = tid >> 6;        // wave id: owns j-cols [16w,16w+16) of each tile
    const int l = tid & 63;
    const int g = l >> 4;
    const int q15 = l & 15;

    __shared__ __align__(16) float peibL[64], wd2L[64], waL[64], be2L[64], bx1L[64], wx2L[64];
    __shared__ __align__(16) float partialL[256];
    __shared__ float xpartL[4][3];
    __shared__ float miL[64], hrowL[64], hid1L[64];

    if (tid < 64) {
        peibL[tid] = peib[i * 64 + tid];
        wd2L[tid]  = We1[128 * 64 + tid];
        waL[tid]   = We1[129 * 64 + tid];
        be2L[tid]  = be2[tid];
        bx1L[tid]  = bx1[tid];
        wx2L[tid]  = Wx2[tid];
        hrowL[tid] = h[i * 64 + tid];
    }
    __syncthreads();

    // ---- weight fragments (persistent in VGPRs, L2-broadcast loads) ----
    const half8* __restrict__ w2h = (const half8*)we2hi;
    const half8* __restrict__ w2l = (const half8*)we2lo;
    const half8* __restrict__ wxh = (const half8*)wx1h;
    half8 whi[4][2], wlo[4][2], wx1f[4][2];
#pragma unroll
    for (int n = 0; n < 4; ++n)
#pragma unroll
        for (int s = 0; s < 2; ++s) {
            whi[n][s]  = w2h[(n * 2 + s) * 64 + l];
            wlo[n][s]  = w2l[(n * 2 + s) * 64 + l];
            wx1f[n][s] = wxh[(n * 2 + s) * 64 + l];
        }

    const float xi0 = x[i * 3 + 0], xi1 = x[i * 3 + 1], xi2 = x[i * 3 + 2];
    const float bx2v = bx2[0];
    const int sl_lo = q15 + 16 * (2 * (g & 1));
    const int sl_hi = sl_lo + 16;
    const bool hiSel = (g >= 2);

    float msum[4][4];
#pragma unroll
    for (int n = 0; n < 4; ++n)
#pragma unroll
        for (int r = 0; r < 4; ++r) msum[n][r] = 0.0f;
    float xa0 = 0.0f, xa1 = 0.0f, xa2 = 0.0f;

    for (int t = 0; t < 16; ++t) {
        const int jw = t * 64 + 16 * w + q15;       // this lane's j
        const float xj0 = x[jw * 3 + 0], xj1 = x[jw * 3 + 1], xj2 = x[jw * 3 + 2];
        const float d0 = xi0 - xj0, d1 = xi1 - xj1, d2v = xi2 - xj2;
        const float dd = fmaf(d0, d0, fmaf(d1, d1, d2v * d2v));
        const float av = a[i * MM + jw];
        const float selfmul = (jw == i) ? 0.0f : 1.0f;

        // ---- build P^T B-fragments: lane holds P[j=q15-row][c-chunk 8g+32s] ----
        half8 P[2];
        const float* __restrict__ pejrow = pej + jw * 64;
#pragma unroll
        for (int s = 0; s < 2; ++s) {
            const f32x4 pj0 = *(const f32x4*)(pejrow + 32 * s + 8 * g);
            const f32x4 pj1 = *(const f32x4*)(pejrow + 32 * s + 8 * g + 4);
            const f32x4 pe0 = *(const f32x4*)&peibL[32 * s + 8 * g];
            const f32x4 pe1 = *(const f32x4*)&peibL[32 * s + 8 * g + 4];
            const f32x4 wd0 = *(const f32x4*)&wd2L[32 * s + 8 * g];
            const f32x4 wd1 = *(const f32x4*)&wd2L[32 * s + 8 * g + 4];
            const f32x4 wa0 = *(const f32x4*)&waL[32 * s + 8 * g];
            const f32x4 wa1 = *(const f32x4*)&waL[32 * s + 8 * g + 4];
#pragma unroll
            for (int e = 0; e < 8; ++e) {
                const float pjv = (e < 4) ? pj0[e] : pj1[e - 4];
                const float pev = (e < 4) ? pe0[e] : pe1[e - 4];
                const float wdv = (e < 4) ? wd0[e] : wd1[e - 4];
                const float wav = (e < 4) ? wa0[e] : wa1[e - 4];
                float pre = pev + pjv;
                pre = fmaf(dd, wdv, pre);
                pre = fmaf(av, wav, pre);
                P[s][e] = (_Float16)fsilu(pre);     // RTN convert
            }
        }

        // ---- D1 = We2^T @ P^T (+be2), fp16 split hi/lo ----
        f32x4 acc1[4];
#pragma unroll
        for (int n = 0; n < 4; ++n) acc1[n] = *(const f32x4*)&be2L[16 * n + 4 * g];
#pragma unroll
        for (int n = 0; n < 4; ++n) {
            acc1[n] = __builtin_amdgcn_mfma_f32_16x16x32_f16(whi[n][0], P[0], acc1[n], 0, 0, 0);
            acc1[n] = __builtin_amdgcn_mfma_f32_16x16x32_f16(whi[n][1], P[1], acc1[n], 0, 0, 0);
            acc1[n] = __builtin_amdgcn_mfma_f32_16x16x32_f16(wlo[n][0], P[0], acc1[n], 0, 0, 0);
            acc1[n] = __builtin_amdgcn_mfma_f32_16x16x32_f16(wlo[n][1], P[1], acc1[n], 0, 0, 0);
        }

        // ---- m = silu(D1); accumulate m_i (f32, self-masked); pack m^T fp16 ----
        float mf[4][4];
        int srcp[4][2];
#pragma unroll
        for (int n = 0; n < 4; ++n) {
#pragma unroll
            for (int r = 0; r < 4; ++r) {
                mf[n][r] = fsilu(acc1[n][r]);
                msum[n][r] = fmaf(mf[n][r], selfmul, msum[n][r]);
            }
            srcp[n][0] = __builtin_bit_cast(int, __builtin_amdgcn_cvt_pkrtz(mf[n][0], mf[n][1]));
            srcp[n][1] = __builtin_bit_cast(int, __builtin_amdgcn_cvt_pkrtz(mf[n][2], mf[n][3]));
        }

        // ---- regroup C-layout rows (4g+r) -> B-layout k-chunks (8g+e) ----
        // target k=32s2+8g+2p+b <- src[n=2s2+(g>>1)][q=p&1] from lane (l&15)+16*(2(g&1)+(p>>1))
        half8 B2[2];
#pragma unroll
        for (int s2 = 0; s2 < 2; ++s2) {
            int4t bi;
#pragma unroll
            for (int p = 0; p < 4; ++p) {
                const int sl = (p < 2) ? sl_lo : sl_hi;
                const int va = __shfl(srcp[2 * s2][p & 1], sl, 64);
                const int vb = __shfl(srcp[2 * s2 + 1][p & 1], sl, 64);
                bi[p] = hiSel ? vb : va;
            }
            B2[s2] = __builtin_bit_cast(half8, bi);
        }

        // ---- T^T = Wx1^T @ m^T (+bx1) ----
        f32x4 acc2[4];
#pragma unroll
        for (int n = 0; n < 4; ++n) acc2[n] = *(const f32x4*)&bx1L[16 * n + 4 * g];
#pragma unroll
        for (int n = 0; n < 4; ++n) {
            acc2[n] = __builtin_amdgcn_mfma_f32_16x16x32_f16(wx1f[n][0], B2[0], acc2[n], 0, 0, 0);
            acc2[n] = __builtin_amdgcn_mfma_f32_16x16x32_f16(wx1f[n][1], B2[1], acc2[n], 0, 0, 0);
        }

        // ---- s[j] = bx2 + sum_kk silu(T)*Wx2[kk]; x-update accumulate ----
        float sp = 0.0f;
#pragma unroll
        for (int n = 0; n < 4; ++n) {
            const f32x4 wq = *(const f32x4*)&wx2L[16 * n + 4 * g];
#pragma unroll
            for (int r = 0; r < 4; ++r) sp = fmaf(fsilu(acc2[n][r]), wq[r], sp);
        }
        sp += __shfl_xor(sp, 16, 64);
        sp += __shfl_xor(sp, 32, 64);       // all 4 g-groups now hold full s[j]
        const float sv = sp + bx2v;
        xa0 = fmaf(d0, sv, xa0);            // 4x duplicated across g; scaled by 0.25 at end
        xa1 = fmaf(d1, sv, xa1);
        xa2 = fmaf(d2v, sv, xa2);
    }

    // ---- m_i: reduce over the 16 j-lanes, write per-wave partials ----
#pragma unroll
    for (int n = 0; n < 4; ++n)
#pragma unroll
        for (int r = 0; r < 4; ++r) {
            float v = msum[n][r];
            v += __shfl_xor(v, 1, 64);
            v += __shfl_xor(v, 2, 64);
            v += __shfl_xor(v, 4, 64);
            v += __shfl_xor(v, 8, 64);
            msum[n][r] = v;
        }
    if (q15 == 0) {
#pragma unroll
        for (int n = 0; n < 4; ++n) {
            f32x4 sv4;
            sv4[0] = msum[n][0]; sv4[1] = msum[n][1];
            sv4[2] = msum[n][2]; sv4[3] = msum[n][3];
            *(f32x4*)&partialL[w * 64 + 16 * n + 4 * g] = sv4;   // k = 16n+4g+r
        }
    }
    {
        float v0 = xa0, v1 = xa1, v2 = xa2;
        for (int sft = 1; sft < 64; sft <<= 1) {
            v0 += __shfl_xor(v0, sft, 64);
            v1 += __shfl_xor(v1, sft, 64);
            v2 += __shfl_xor(v2, sft, 64);
        }
        if (l == 0) { xpartL[w][0] = v0; xpartL[w][1] = v1; xpartL[w][2] = v2; }
    }
    __syncthreads();

    if (tid < 64)
        miL[tid] = partialL[tid] + partialL[64 + tid] + partialL[128 + tid] + partialL[192 + tid];
    __syncthreads();

    // phi_h layer 1
    if (tid < 64) {
        const int kk = tid;
        float a0 = bh1[kk], a1 = 0.0f;
#pragma unroll 8
        for (int c = 0; c < 64; ++c) {
            a0 = fmaf(hrowL[c], Wh1[c * 64 + kk], a0);
            a1 = fmaf(miL[c], Wh1[(64 + c) * 64 + kk], a1);
        }
        hid1L[kk] = fsilu(a0 + a1);
    }
    __syncthreads();

    // phi_h layer 2 -> h_new
    if (tid < 64) {
        float accv = bh2[tid];
#pragma unroll 8
        for (int kk = 0; kk < 64; ++kk) accv = fmaf(hid1L[kk], Wh2[kk * 64 + tid], accv);
        out[3072 + i * 64 + tid] = accv;
    }
    // x_new (0.25 compensates the 4x g-group duplication of xa)
    if (tid == 0) {
        const float C = 0.25f / 1023.0f;
        out[i * 3 + 0] = xi0 + C * (xpartL[0][0] + xpartL[1][0] + xpartL[2][0] + xpartL[3][0]);
        out[i * 3 + 1] = xi1 + C * (xpartL[0][1] + xpartL[1][1] + xpartL[2][1] + xpartL[3][1]);
        out[i * 3 + 2] = xi2 + C * (xpartL[0][2] + xpartL[1][2] + xpartL[2][2] + xpartL[3][2]);
    }
}

extern "C" void kernel_launch(void* const* d_in, const int* in_sizes, int n_in,
                              void* d_out, int out_size, void* d_ws, size_t ws_size,
                              hipStream_t stream) {
    const float* x   = (const float*)d_in[0];
    const float* a   = (const float*)d_in[1];
    const float* h   = (const float*)d_in[2];
    const float* We1 = (const float*)d_in[3];
    const float* be1 = (const float*)d_in[4];
    const float* We2 = (const float*)d_in[5];
    const float* be2 = (const float*)d_in[6];
    const float* Wx1 = (const float*)d_in[7];
    const float* bx1 = (const float*)d_in[8];
    const float* Wx2 = (const float*)d_in[9];
    const float* bx2 = (const float*)d_in[10];
    const float* Wh1 = (const float*)d_in[11];
    const float* bh1 = (const float*)d_in[12];
    const float* Wh2 = (const float*)d_in[13];
    const float* bh2 = (const float*)d_in[14];
    float* out = (float*)d_out;

    float* peib = (float*)d_ws;                    // [1024*64]
    float* pej  = peib + 65536;                    // [1024*64]
    _Float16* we2hi = (_Float16*)(pej + 65536);    // 4096 fp16
    _Float16* we2lo = we2hi + 4096;                // 4096 fp16
    _Float16* wx1h  = we2lo + 4096;                // 4096 fp16

    egnn_prepack<<<dim3(288), dim3(256), 0, stream>>>(
        h, We1, be1, We2, Wx1, peib, pej, we2hi, we2lo, wx1h);
    egnn_main<<<dim3(1024), dim3(256), 0, stream>>>(
        x, a, h, We1, peib, pej, we2hi, we2lo, wx1h,
        be2, bx1, Wx2, bx2, Wh1, bh1, Wh2, bh2, out);
}